// Round 3
// baseline (350.037 us; speedup 1.0000x reference)
//
#include <hip/hip_runtime.h>
#include <float.h>

// VectorQuantizer: B=16,T=4096,D=256,K=1024 fp32.
// Round 3: f16 MFMA GEMM w/ global_load_lds double-buffered pipeline +
//          register-resident token frags + batched coalesced fp32 rescue.

typedef _Float16 f16;
typedef f16 f16x8 __attribute__((ext_vector_type(8)));
typedef f16 f16x4 __attribute__((ext_vector_type(4)));
typedef float f32x4 __attribute__((ext_vector_type(4)));

#define DDIM   256
#define KCODES 1024
#define NTOK   65536
#define MARGIN 0.2f

#define AS3(p) ((__attribute__((address_space(3))) unsigned int*)(p))
#define AS1(p) ((const __attribute__((address_space(1))) unsigned int*)(p))

// ---------------- prep: codebook fp32->f16, c2, zero counter ----------------
__global__ __launch_bounds__(256) void vq_prep(const float* __restrict__ cb,
                                               f16* __restrict__ ch,
                                               float* __restrict__ c2,
                                               unsigned* __restrict__ count) {
    const int k    = blockIdx.x * 4 + (threadIdx.x >> 6);
    const int lane = threadIdx.x & 63;
    const float4 v = *(const float4*)(cb + (size_t)k * DDIM + 4 * lane);
    f16x4 h; h[0] = (f16)v.x; h[1] = (f16)v.y; h[2] = (f16)v.z; h[3] = (f16)v.w;
    *(f16x4*)(ch + (size_t)k * DDIM + 4 * lane) = h;
    float s = v.x * v.x + v.y * v.y + v.z * v.z + v.w * v.w;
    #pragma unroll
    for (int off = 32; off > 0; off >>= 1) s += __shfl_down(s, off, 64);
    if (lane == 0) c2[k] = s;
    if (blockIdx.x == 0 && threadIdx.x == 0) *count = 0u;
}

// ---------------- main: pipelined MFMA + fused argmin + gather ----------------
// 64 tokens/block, 1024 blocks. Codes streamed via global_load_lds (16B),
// XOR-swizzled LDS tiles (64 codes x 128 f16 per phase), 2 buffers,
// 1 __syncthreads per phase: loads for phase p+1 fly during compute(p).
__global__ __launch_bounds__(256, 4) void vq_main(const float* __restrict__ xg,
                                                  const f16* __restrict__ ch,
                                                  const float* __restrict__ c2,
                                                  const float* __restrict__ cb,
                                                  float* __restrict__ out,
                                                  unsigned* __restrict__ count,
                                                  unsigned* __restrict__ list) {
    __shared__ f16 As[2][64 * 128];
    __shared__ float wmv[2][64], wms[2][64];
    __shared__ int   wmi[2][64];
    __shared__ int   idx_s[64];

    const int t    = threadIdx.x;
    const int wave = t >> 6, lane = t & 63;
    const int wm   = wave >> 1;                 // code-half of chunk
    const int tn   = wave & 1;                  // token-half of block
    const int q    = lane >> 4;                 // operand quad
    const int m16  = lane & 15;
    const int tok0 = blockIdx.x * 64;

    // ---- token B-fragments: fp32 -> f16 in registers, loaded once ----
    // B[n=lane&15][k=q*8+j], global k = kg*32 + q*8 + j
    f16x8 bfrag[2][8];
    #pragma unroll
    for (int ti = 0; ti < 2; ++ti) {
        const size_t row = (size_t)(tok0 + tn * 32 + ti * 16 + m16) * DDIM;
        #pragma unroll
        for (int ks = 0; ks < 8; ++ks) {
            const float* p = xg + row + ks * 32 + q * 8;
            const float4 u0 = *(const float4*)(p);
            const float4 u1 = *(const float4*)(p + 4);
            f16x8 b;
            b[0] = (f16)u0.x; b[1] = (f16)u0.y; b[2] = (f16)u0.z; b[3] = (f16)u0.w;
            b[4] = (f16)u1.x; b[5] = (f16)u1.y; b[6] = (f16)u1.z; b[7] = (f16)u1.w;
            bfrag[ti][ks] = b;
        }
    }

    float rb1[2] = {FLT_MAX, FLT_MAX}, rb2[2] = {FLT_MAX, FLT_MAX};
    int   ri1[2] = {0, 0};

    // phase p: chunk nc=p>>1 (64 codes), K-half st=p&1 (128 d), buffer p&1.
    // Physical granule gp = (g&8)|((g^row)&7)  (self-inverse XOR swizzle ->
    // ds_read_b128 conflict-free without padding; DMA dest stays contiguous).
    auto issue = [&](int p) {
        const int nc = p >> 1, st = p & 1, buf = p & 1;
        #pragma unroll
        for (int i = 0; i < 4; ++i) {
            const int slot = i * 256 + t;          // 1024 granules of 16B
            const int row  = slot >> 4, gp = slot & 15;
            const int g    = (gp & 8) | ((gp ^ row) & 7);
            const f16* src = ch + (size_t)(nc * 64 + row) * DDIM + st * 128 + g * 8;
            f16* dst = &As[buf][(i * 256 + wave * 64) * 8];  // wave-uniform base
            __builtin_amdgcn_global_load_lds(AS1(src), AS3(dst), 16, 0, 0);
        }
    };

    f32x4 acc[2][2];                                // [ci][ti]
    issue(0);
    for (int p = 0; p < 32; ++p) {
        __syncthreads();        // drains loads(p) (issued 1 full phase ago)
        if (p + 1 < 32) issue(p + 1);
        const int nc = p >> 1, st = p & 1, buf = p & 1;
        if (st == 0) {
            #pragma unroll
            for (int ci = 0; ci < 2; ++ci)
                #pragma unroll
                for (int ti = 0; ti < 2; ++ti) acc[ci][ti] = (f32x4)0.0f;
        }
        #pragma unroll
        for (int kk = 0; kk < 4; ++kk) {
            f16x8 af[2];
            #pragma unroll
            for (int ci = 0; ci < 2; ++ci) {
                const int row = wm * 32 + ci * 16 + m16;
                const int g   = kk * 4 + q;
                const int gp  = (g & 8) | ((g ^ row) & 7);
                af[ci] = *(const f16x8*)&As[buf][row * 128 + gp * 8];
            }
            const int kg = st * 4 + kk;
            #pragma unroll
            for (int ci = 0; ci < 2; ++ci)
                #pragma unroll
                for (int ti = 0; ti < 2; ++ti)
                    acc[ci][ti] = __builtin_amdgcn_mfma_f32_16x16x32_f16(
                        af[ci], bfrag[ti][kg], acc[ci][ti], 0, 0, 0);
        }
        if (st == 1) {                              // chunk epilogue (regs only)
            const int kb = nc * 64 + wm * 32;
            float cc[2][4];
            #pragma unroll
            for (int ci = 0; ci < 2; ++ci)
                #pragma unroll
                for (int r = 0; r < 4; ++r) cc[ci][r] = c2[kb + ci * 16 + q * 4 + r];
            #pragma unroll
            for (int ti = 0; ti < 2; ++ti) {
                float b1 = FLT_MAX, b2 = FLT_MAX; int i1 = 0;
                #pragma unroll
                for (int ci = 0; ci < 2; ++ci) {    // ascending codes per lane
                    #pragma unroll
                    for (int r = 0; r < 4; ++r) {
                        const float d = fmaf(-2.0f, acc[ci][ti][r], cc[ci][r]);
                        const int   c = kb + ci * 16 + q * 4 + r;
                        const bool lt = d < b1;
                        b2 = fminf(b2, lt ? b1 : d);
                        i1 = lt ? c : i1;
                        b1 = lt ? d : b1;
                    }
                }
                #pragma unroll
                for (int s = 0; s < 2; ++s) {       // quad butterfly merge
                    const int off = 16 << s;
                    const float ob1 = __shfl_xor(b1, off, 64);
                    const float ob2 = __shfl_xor(b2, off, 64);
                    const int   oi1 = __shfl_xor(i1, off, 64);
                    const bool better = (ob1 < b1) || (ob1 == b1 && oi1 < i1);
                    b2 = fminf(fminf(b2, ob2), fmaxf(b1, ob1));
                    b1 = better ? ob1 : b1;
                    i1 = better ? oi1 : i1;
                }
                rb2[ti] = fminf(fminf(rb2[ti], b2), fmaxf(rb1[ti], b1));
                if (b1 < rb1[ti]) { rb1[ti] = b1; ri1[ti] = i1; }  // ties -> earlier chunk
            }
        }
    }

    __syncthreads();
    if (q == 0) {
        #pragma unroll
        for (int ti = 0; ti < 2; ++ti) {
            const int tokl = tn * 32 + ti * 16 + m16;
            wmv[wm][tokl] = rb1[ti];
            wms[wm][tokl] = rb2[ti];
            wmi[wm][tokl] = ri1[ti];
        }
    }
    __syncthreads();
    if (t < 64) {                                   // merge code-halves + flag
        const float a1 = wmv[0][t], a2 = wms[0][t];
        const int   ai = wmi[0][t];
        const float b1 = wmv[1][t], b2 = wms[1][t];
        const int   bi = wmi[1][t];
        const bool bb = (b1 < a1) || (b1 == a1 && bi < ai);
        const float c1 = bb ? b1 : a1;
        const int   ci = bb ? bi : ai;
        const float cs = fminf(fminf(a2, b2), fmaxf(a1, b1));
        idx_s[t] = ci;
        if (cs - c1 < MARGIN) {
            const unsigned pp = atomicAdd(count, 1u);
            list[pp] = tok0 + t;
        }
    }
    __syncthreads();

    // gather epilogue: out[tok] = cb[argmin], coalesced float4
    #pragma unroll
    for (int i = 0; i < 16; ++i) {
        const int f   = i * 256 + t;                // 4096 float4 = 64 tok x 64
        const int tok = f >> 6, d4 = f & 63;
        const int code = idx_s[tok];
        const float4 v = *(const float4*)(cb + (size_t)code * DDIM + 4 * d4);
        *(float4*)(out + (size_t)(tok0 + tok) * DDIM + 4 * d4) = v;
    }
}

// ---------------- rescue: exact fp32 argmin, batched + LDS-coalesced ----------------
// 4 tokens/block; cb staged in 64-code x 64-d chunks (coalesced); threads =
// 64 codes x 4 tokens.
__global__ __launch_bounds__(256) void vq_rescue(const float* __restrict__ xg,
                                                 const float* __restrict__ cb,
                                                 const float* __restrict__ c2,
                                                 const unsigned* __restrict__ count,
                                                 const unsigned* __restrict__ list,
                                                 float* __restrict__ out) {
    __shared__ float xls[4][260];
    __shared__ float cs[64][68];
    __shared__ float redv[256];
    __shared__ int   redi[256];
    __shared__ int   bidx[4];

    const int t  = threadIdx.x;
    const int c  = t >> 2, tk = t & 3;
    const unsigned n = *count;

    for (unsigned base = blockIdx.x * 4; base < n; base += gridDim.x * 4) {
        const int nb = (int)min(4u, n - base);
        __syncthreads();
        {   // stage tokens (coalesced)
            const int row = t >> 6, d4 = t & 63;
            if (row < nb)
                *(float4*)&xls[row][4 * d4] =
                    *(const float4*)(xg + (size_t)list[base + row] * DDIM + 4 * d4);
        }

        float bestv = FLT_MAX; int besti = 0;
        for (int cc = 0; cc < 16; ++cc) {           // 16 chunks of 64 codes
            float dot = 0.0f;
            for (int dc = 0; dc < 4; ++dc) {        // 4 chunks of 64 d
                __syncthreads();
                #pragma unroll
                for (int i = 0; i < 4; ++i) {       // stage cb chunk, coalesced
                    const int slot = t + 256 * i;
                    const int row = slot >> 4, d4 = slot & 15;
                    *(float4*)&cs[row][4 * d4] =
                        *(const float4*)(cb + (size_t)(cc * 64 + row) * DDIM + dc * 64 + 4 * d4);
                }
                __syncthreads();
                #pragma unroll
                for (int d4 = 0; d4 < 16; ++d4) {
                    const float4 cv = *(const float4*)&cs[c][4 * d4];
                    const float4 xv = *(const float4*)&xls[tk][dc * 64 + 4 * d4];
                    dot = fmaf(cv.x, xv.x, dot);
                    dot = fmaf(cv.y, xv.y, dot);
                    dot = fmaf(cv.z, xv.z, dot);
                    dot = fmaf(cv.w, xv.w, dot);
                }
            }
            const int code = cc * 64 + c;           // codes ascend across cc
            const float d2 = fmaf(-2.0f, dot, c2[code]);
            if (d2 < bestv) { bestv = d2; besti = code; }
        }
        redv[t] = bestv; redi[t] = besti;
        __syncthreads();
        if (t < 4) {                                // reduce 64 code-threads per token
            float bv = redv[t]; int bi = redi[t];
            for (int j = 1; j < 64; ++j) {
                const float v = redv[t + 4 * j];
                const int   i2 = redi[t + 4 * j];
                if (v < bv || (v == bv && i2 < bi)) { bv = v; bi = i2; }
            }
            bidx[t] = bi;
        }
        __syncthreads();
        {   // overwrite out rows for rescued tokens
            const int row = t >> 6, d4 = t & 63;
            if (row < nb) {
                const float4 v = *(const float4*)(cb + (size_t)bidx[row] * DDIM + 4 * d4);
                *(float4*)(out + (size_t)list[base + row] * DDIM + 4 * d4) = v;
            }
        }
    }
}

extern "C" void kernel_launch(void* const* d_in, const int* in_sizes, int n_in,
                              void* d_out, int out_size, void* d_ws, size_t ws_size,
                              hipStream_t stream) {
    const float* x  = (const float*)d_in[0];   // [B,T,D] fp32
    const float* cb = (const float*)d_in[1];   // [K,D]   fp32
    float* out = (float*)d_out;

    char* ws = (char*)d_ws;
    f16*      ch    = (f16*)ws;                              // 524288 B
    float*    c2    = (float*)(ws + 524288);                 // 4096 B
    unsigned* count = (unsigned*)(ws + 528448);              // 4 B
    unsigned* list  = (unsigned*)(ws + 528512);              // 262144 B

    hipLaunchKernelGGL(vq_prep,   dim3(KCODES / 4), dim3(256), 0, stream, cb, ch, c2, count);
    hipLaunchKernelGGL(vq_main,   dim3(NTOK / 64),  dim3(256), 0, stream,
                       x, ch, c2, cb, out, count, list);
    hipLaunchKernelGGL(vq_rescue, dim3(512),        dim3(256), 0, stream,
                       x, cb, c2, count, list, out);
}

// Round 4
// 289.757 us; speedup vs baseline: 1.2080x; 1.2080x over previous
//
#include <hip/hip_runtime.h>
#include <float.h>

// VectorQuantizer: B=16,T=4096,D=256,K=1024 fp32.
// Round 4: f16 MFMA GEMM, regular-load staging (L2-friendly; global_load_lds
// proved L2-bypassing in R3), double-buffered LDS code tiles, ONE raw
// s_barrier per stage (prefetch loads stay in flight across it),
// register top-2 argmin + margin-gated exact-fp32 rescue.

typedef _Float16 f16;
typedef f16 f16x8 __attribute__((ext_vector_type(8)));
typedef f16 f16x4 __attribute__((ext_vector_type(4)));
typedef float f32x4 __attribute__((ext_vector_type(4)));

#define DDIM   256
#define KCODES 1024
#define NTOK   65536
#define MARGIN 0.2f
#define ASTR   72   // f16 per LDS row: 64 data + 8 pad (R2-verified adequate)

// Raw barrier: orders LDS only; does NOT drain vmcnt -> prefetch stays in flight.
#define BAR() asm volatile("s_waitcnt lgkmcnt(0)\n\ts_barrier" ::: "memory")

// ---------------- prep: codebook fp32->f16, c2, zero counter ----------------
__global__ __launch_bounds__(256) void vq_prep(const float* __restrict__ cb,
                                               f16* __restrict__ ch,
                                               float* __restrict__ c2,
                                               unsigned* __restrict__ count) {
    const int k    = blockIdx.x * 4 + (threadIdx.x >> 6);
    const int lane = threadIdx.x & 63;
    const float4 v = *(const float4*)(cb + (size_t)k * DDIM + 4 * lane);
    f16x4 h; h[0] = (f16)v.x; h[1] = (f16)v.y; h[2] = (f16)v.z; h[3] = (f16)v.w;
    *(f16x4*)(ch + (size_t)k * DDIM + 4 * lane) = h;
    float s = v.x * v.x + v.y * v.y + v.z * v.z + v.w * v.w;
    #pragma unroll
    for (int off = 32; off > 0; off >>= 1) s += __shfl_down(s, off, 64);
    if (lane == 0) c2[k] = s;
    if (blockIdx.x == 0 && threadIdx.x == 0) *count = 0u;
}

// ---------------- main: pipelined MFMA + fused argmin + gather ----------------
// 128 tokens/block, 512 blocks (= 2/CU). Stage s: chunk nc=s>>2 (128 codes),
// K-quarter st=s&3 (64 d), LDS buffer s&1.
__global__ __launch_bounds__(256, 2) void vq_main(const float* __restrict__ xg,
                                                  const f16* __restrict__ ch,
                                                  const float* __restrict__ c2,
                                                  const float* __restrict__ cb,
                                                  float* __restrict__ out,
                                                  unsigned* __restrict__ count,
                                                  unsigned* __restrict__ list) {
    __shared__ f16 As[2][128 * ASTR];
    __shared__ float wmv[2][128], wms[2][128];
    __shared__ int   wmi[2][128];
    __shared__ int   idx_s[128];

    const int t    = threadIdx.x;
    const int wave = t >> 6, lane = t & 63;
    const int wm   = wave >> 1;                 // code-half
    const int tn   = wave & 1;                  // token-half
    const int q    = lane >> 4;                 // operand quad
    const int m16  = lane & 15;
    const int tok0 = blockIdx.x * 128;

    // ---- token B-fragments, fp32 -> f16 in registers (R2-verified layout) ----
    f16x8 bfrag[4][8];
    #pragma unroll
    for (int ti = 0; ti < 4; ++ti) {
        const size_t row = (size_t)(tok0 + tn * 64 + ti * 16 + m16) * DDIM;
        #pragma unroll
        for (int ks = 0; ks < 8; ++ks) {
            const float* p = xg + row + ks * 32 + q * 8;
            const float4 u0 = *(const float4*)(p);
            const float4 u1 = *(const float4*)(p + 4);
            f16x8 b;
            b[0] = (f16)u0.x; b[1] = (f16)u0.y; b[2] = (f16)u0.z; b[3] = (f16)u0.w;
            b[4] = (f16)u1.x; b[5] = (f16)u1.y; b[6] = (f16)u1.z; b[7] = (f16)u1.w;
            bfrag[ti][ks] = b;
        }
    }

    float rb1[4] = {FLT_MAX, FLT_MAX, FLT_MAX, FLT_MAX};
    float rb2[4] = {FLT_MAX, FLT_MAX, FLT_MAX, FLT_MAX};
    int   ri1[4] = {0, 0, 0, 0};

    const int row_s = t >> 3;                   // staging: 32 rows per i-step
    const int c16_s = t & 7;
    f16x8 r[4];
    auto load_r = [&](int s) {
        const int nc = s >> 2, st = s & 3;
        #pragma unroll
        for (int i = 0; i < 4; ++i)
            r[i] = *(const f16x8*)(ch + (size_t)(nc * 128 + 32 * i + row_s) * DDIM
                                   + st * 64 + c16_s * 8);
    };
    auto store_r = [&](int buf) {
        #pragma unroll
        for (int i = 0; i < 4; ++i)
            *(f16x8*)(&As[buf][(32 * i + row_s) * ASTR + c16_s * 8]) = r[i];
    };

    f32x4 acc[4][4];                            // [ci][ti]
    load_r(0);
    store_r(0);
    for (int s = 0; s < 32; ++s) {
        const int nc = s >> 2, st = s & 3, buf = s & 1;
        if (s < 31) load_r(s + 1);              // prefetch: in flight across BAR+compute
        BAR();                                  // buf[s&1] complete (stores from iter s-1)
        if (st == 0) {
            #pragma unroll
            for (int ci = 0; ci < 4; ++ci)
                #pragma unroll
                for (int ti = 0; ti < 4; ++ti) acc[ci][ti] = (f32x4)0.0f;
        }
        #pragma unroll
        for (int kk = 0; kk < 2; ++kk) {
            f16x8 af[4];
            #pragma unroll
            for (int ci = 0; ci < 4; ++ci)
                af[ci] = *(const f16x8*)&As[buf][(wm * 64 + ci * 16 + m16) * ASTR
                                                 + kk * 32 + q * 8];
            const int kg = st * 2 + kk;
            #pragma unroll
            for (int ci = 0; ci < 4; ++ci)
                #pragma unroll
                for (int ti = 0; ti < 4; ++ti)
                    acc[ci][ti] = __builtin_amdgcn_mfma_f32_16x16x32_f16(
                        af[ci], bfrag[ti][kg], acc[ci][ti], 0, 0, 0);
        }
        if (st == 3) {                          // chunk epilogue: top-2, regs only
            const int kb = nc * 128 + wm * 64;
            #pragma unroll
            for (int ti = 0; ti < 4; ++ti) {
                float b1 = FLT_MAX, b2 = FLT_MAX; int i1 = 0;
                #pragma unroll
                for (int ci = 0; ci < 4; ++ci) {
                    #pragma unroll
                    for (int rr = 0; rr < 4; ++rr) {
                        const int   c = kb + ci * 16 + q * 4 + rr;
                        const float d = fmaf(-2.0f, acc[ci][ti][rr], c2[c]);
                        const bool lt = d < b1;
                        b2 = fminf(b2, lt ? b1 : d);
                        i1 = lt ? c : i1;
                        b1 = lt ? d : b1;
                    }
                }
                #pragma unroll
                for (int s2 = 0; s2 < 2; ++s2) { // quad butterfly merge
                    const int off = 16 << s2;
                    const float ob1 = __shfl_xor(b1, off, 64);
                    const float ob2 = __shfl_xor(b2, off, 64);
                    const int   oi1 = __shfl_xor(i1, off, 64);
                    const bool better = (ob1 < b1) || (ob1 == b1 && oi1 < i1);
                    b2 = fminf(fminf(b2, ob2), fmaxf(b1, ob1));
                    b1 = better ? ob1 : b1;
                    i1 = better ? oi1 : i1;
                }
                rb2[ti] = fminf(fminf(rb2[ti], b2), fmaxf(rb1[ti], b1));
                if (b1 < rb1[ti]) { rb1[ti] = b1; ri1[ti] = i1; }  // ties -> earlier chunk
            }
        }
        if (s < 31) store_r((s + 1) & 1);       // safe: all waves passed BAR(s)
    }

    __syncthreads();
    if (q == 0) {
        #pragma unroll
        for (int ti = 0; ti < 4; ++ti) {
            const int tl = tn * 64 + ti * 16 + m16;
            wmv[wm][tl] = rb1[ti];
            wms[wm][tl] = rb2[ti];
            wmi[wm][tl] = ri1[ti];
        }
    }
    __syncthreads();
    if (t < 128) {                              // merge code-halves + margin flag
        const float a1 = wmv[0][t], a2 = wms[0][t];
        const int   ai = wmi[0][t];
        const float b1 = wmv[1][t], b2 = wms[1][t];
        const int   bi = wmi[1][t];
        const bool bb = (b1 < a1) || (b1 == a1 && bi < ai);
        const float c1 = bb ? b1 : a1;
        const int   ci = bb ? bi : ai;
        const float cs = fminf(fminf(a2, b2), fmaxf(a1, b1));
        idx_s[t] = ci;
        if (cs - c1 < MARGIN) {
            const unsigned pp = atomicAdd(count, 1u);
            list[pp] = tok0 + t;
        }
    }
    __syncthreads();

    // gather epilogue: out[tok] = cb[argmin], coalesced float4
    #pragma unroll
    for (int i = 0; i < 32; ++i) {
        const int f   = i * 256 + t;            // 8192 float4 = 128 tok x 64
        const int tok = f >> 6, d4 = f & 63;
        const int code = idx_s[tok];
        const float4 v = *(const float4*)(cb + (size_t)code * DDIM + 4 * d4);
        *(float4*)(out + (size_t)(tok0 + tok) * DDIM + 4 * d4) = v;
    }
}

// ---------------- rescue: exact fp32 argmin, batched + LDS-coalesced ----------------
__global__ __launch_bounds__(256) void vq_rescue(const float* __restrict__ xg,
                                                 const float* __restrict__ cb,
                                                 const float* __restrict__ c2,
                                                 const unsigned* __restrict__ count,
                                                 const unsigned* __restrict__ list,
                                                 float* __restrict__ out) {
    __shared__ float xls[4][260];
    __shared__ float cs[64][68];
    __shared__ float redv[256];
    __shared__ int   redi[256];
    __shared__ int   bidx[4];

    const int t  = threadIdx.x;
    const int c  = t >> 2, tk = t & 3;
    const unsigned n = *count;

    for (unsigned base = blockIdx.x * 4; base < n; base += gridDim.x * 4) {
        const int nb = (int)min(4u, n - base);
        __syncthreads();
        {   // stage tokens (coalesced)
            const int row = t >> 6, d4 = t & 63;
            if (row < nb)
                *(float4*)&xls[row][4 * d4] =
                    *(const float4*)(xg + (size_t)list[base + row] * DDIM + 4 * d4);
        }

        float bestv = FLT_MAX; int besti = 0;
        for (int cc = 0; cc < 16; ++cc) {           // 16 chunks of 64 codes
            float dot = 0.0f;
            for (int dc = 0; dc < 4; ++dc) {        // 4 chunks of 64 d
                __syncthreads();
                #pragma unroll
                for (int i = 0; i < 4; ++i) {       // stage cb chunk, coalesced
                    const int slot = t + 256 * i;
                    const int row = slot >> 4, d4 = slot & 15;
                    *(float4*)&cs[row][4 * d4] =
                        *(const float4*)(cb + (size_t)(cc * 64 + row) * DDIM + dc * 64 + 4 * d4);
                }
                __syncthreads();
                #pragma unroll
                for (int d4 = 0; d4 < 16; ++d4) {
                    const float4 cv = *(const float4*)&cs[c][4 * d4];
                    const float4 xv = *(const float4*)&xls[tk][dc * 64 + 4 * d4];
                    dot = fmaf(cv.x, xv.x, dot);
                    dot = fmaf(cv.y, xv.y, dot);
                    dot = fmaf(cv.z, xv.z, dot);
                    dot = fmaf(cv.w, xv.w, dot);
                }
            }
            const int code = cc * 64 + c;           // codes ascend across cc
            const float d2 = fmaf(-2.0f, dot, c2[code]);
            if (d2 < bestv) { bestv = d2; besti = code; }
        }
        redv[t] = bestv; redi[t] = besti;
        __syncthreads();
        if (t < 4) {                                // reduce 64 code-threads per token
            float bv = redv[t]; int bi = redi[t];
            for (int j = 1; j < 64; ++j) {
                const float v = redv[t + 4 * j];
                const int   i2 = redi[t + 4 * j];
                if (v < bv || (v == bv && i2 < bi)) { bv = v; bi = i2; }
            }
            bidx[t] = bi;
        }
        __syncthreads();
        {   // overwrite out rows for rescued tokens
            const int row = t >> 6, d4 = t & 63;
            if (row < nb) {
                const float4 v = *(const float4*)(cb + (size_t)bidx[row] * DDIM + 4 * d4);
                *(float4*)(out + (size_t)list[base + row] * DDIM + 4 * d4) = v;
            }
        }
    }
}

extern "C" void kernel_launch(void* const* d_in, const int* in_sizes, int n_in,
                              void* d_out, int out_size, void* d_ws, size_t ws_size,
                              hipStream_t stream) {
    const float* x  = (const float*)d_in[0];   // [B,T,D] fp32
    const float* cb = (const float*)d_in[1];   // [K,D]   fp32
    float* out = (float*)d_out;

    char* ws = (char*)d_ws;
    f16*      ch    = (f16*)ws;                              // 524288 B
    float*    c2    = (float*)(ws + 524288);                 // 4096 B
    unsigned* count = (unsigned*)(ws + 528448);              // 4 B
    unsigned* list  = (unsigned*)(ws + 528512);              // 262144 B

    hipLaunchKernelGGL(vq_prep,   dim3(KCODES / 4), dim3(256), 0, stream, cb, ch, c2, count);
    hipLaunchKernelGGL(vq_main,   dim3(NTOK / 128), dim3(256), 0, stream,
                       x, ch, c2, cb, out, count, list);
    hipLaunchKernelGGL(vq_rescue, dim3(512),        dim3(256), 0, stream,
                       x, cb, c2, count, list, out);
}